// Round 2
// baseline (791.528 us; speedup 1.0000x reference)
//
#include <hip/hip_runtime.h>
#include <hip/hip_bf16.h>

typedef unsigned int uint;

#define T_STEPS 100

// ---------------- ws layout (bytes) ----------------
#define OFF_H1   (size_t)0                       // [16][64][28][28] f32   = 3,211,264
#define OFF_P1   (size_t)3211264                 // [100][16][64][16][16] u8 = 26,214,400 (halo-padded)
#define OFF_W2T  (size_t)29425664                // [64ci][3][3][64co] f32 = 147,456
#define OFF_H2   (size_t)29573120                // [1600][64][196] f32    = 80,281,600
#define OFF_P2   (size_t)109854720               // [100][16][3136] u8     = 5,017,600
#define OFF_H3   (size_t)114872320               // [100][16][1024] f32    = 6,553,600
#define OFF_S3   (size_t)121425920               // [100][16][1024] u8     = 1,638,400
#define OFF_H4   (size_t)123064320               // [100][16][10] f32      = 64,000

__device__ __forceinline__ int lif_step_i(float& v, float x) {
  // v = v + (x - v)/2  (multiply by 0.5 is exact, identical rounding to reference)
  v = __fadd_rn(v, __fmul_rn(__fsub_rn(x, v), 0.5f));
  if (v >= 1.0f) { v = 0.0f; return 1; }
  return 0;
}

// ---------------- setup kernels ----------------
__global__ __launch_bounds__(256) void k_transpose_w2(const float* __restrict__ w2,
                                                      float* __restrict__ w2t) {
  int i = blockIdx.x * 256 + threadIdx.x;      // i = (ci*9 + t9)*64 + co, 36864 total
  int co = i & 63;
  int r  = i >> 6;
  int t9 = r % 9, ci = r / 9;
  w2t[i] = w2[(co * 64 + ci) * 9 + t9];
}

__global__ __launch_bounds__(256) void k_zero_h3(float4* __restrict__ p) {
  p[blockIdx.x * 256 + threadIdx.x] = make_float4(0.f, 0.f, 0.f, 0.f);
}

// ---------------- conv1 + BN1 ----------------
__global__ __launch_bounds__(256) void k_conv1(const float* __restrict__ x, const float* __restrict__ w1,
                                               const float* __restrict__ g1, const float* __restrict__ b1,
                                               const float* __restrict__ m1, const float* __restrict__ v1,
                                               float* __restrict__ h1) {
  int i = blockIdx.x * 256 + threadIdx.x;      // < 802816
  int pos = i % 784;
  int bc  = i / 784;
  int c = bc & 63, b = bc >> 6;
  int y = pos / 28, xx = pos % 28;
  float a = 0.f;
#pragma unroll
  for (int dy = 0; dy < 3; ++dy) {
    int iy = y + dy - 1;
#pragma unroll
    for (int dx = 0; dx < 3; ++dx) {
      int ix = xx + dx - 1;
      if (iy >= 0 && iy < 28 && ix >= 0 && ix < 28)
        a = fmaf(w1[c * 9 + dy * 3 + dx], x[b * 784 + iy * 28 + ix], a);
    }
  }
  float inv  = g1[c] / sqrtf(v1[c] + 1e-5f);
  float bias = __fsub_rn(b1[c], __fmul_rn(m1[c], inv));
  h1[i] = __fadd_rn(__fmul_rn(a, inv), bias);
}

// ---------------- LIF1 + maxpool -> p1 (u8, halo-padded 16x16) ----------------
__global__ __launch_bounds__(256) void k_lif1pool(const float* __restrict__ h1,
                                                  unsigned char* __restrict__ p1) {
  int t = blockIdx.x * 256 + threadIdx.x;      // < 262144 = 16*64*16*16
  int lx = t & 15, ly = (t >> 4) & 15, c = (t >> 8) & 63, b = t >> 14;
  size_t outbase = ((size_t)b * 64 + c) * 256 + ly * 16 + lx;
  const size_t tstride = (size_t)16 * 64 * 256;
  if (ly == 0 || ly == 15 || lx == 0 || lx == 15) {
    for (int tt = 0; tt < T_STEPS; ++tt) p1[outbase + (size_t)tt * tstride] = 0;
    return;
  }
  int py = ly - 1, px = lx - 1;
  const float* hp = h1 + ((size_t)(b * 64 + c) * 28 + 2 * py) * 28 + 2 * px;
  float h00 = hp[0], h01 = hp[1], h10 = hp[28], h11 = hp[29];
  float v00 = 0.f, v01 = 0.f, v10 = 0.f, v11 = 0.f;
  for (int tt = 0; tt < T_STEPS; ++tt) {
    int s = 0;
    s |= lif_step_i(v00, h00);
    s |= lif_step_i(v01, h01);
    s |= lif_step_i(v10, h10);
    s |= lif_step_i(v11, h11);
    p1[outbase + (size_t)tt * tstride] = (unsigned char)s;
  }
}

// ---------------- conv2 + BN2 (the big one) ----------------
// block = 256 threads, 2 images; LDS u8 img [2][64][16][32] = 64KB
// thread job (224 active): (img, co8, oy) -> computes 8 co x 14 ox outputs
__global__ __launch_bounds__(256, 2) void k_conv2(const unsigned char* __restrict__ p1,
                                                  const float* __restrict__ w2t,
                                                  const float* __restrict__ g2, const float* __restrict__ b2,
                                                  const float* __restrict__ m2, const float* __restrict__ v2,
                                                  float* __restrict__ h2) {
  __shared__ unsigned char simg[2][64][16][32];
  const int tid = threadIdx.x;
  const int tb0 = blockIdx.x * 2;
  // stage: 2048 rows of 16B (img, ci, ly)
#pragma unroll
  for (int i = 0; i < 8; ++i) {
    int rix = i * 256 + tid;
    int img = rix >> 10;
    int rem = rix & 1023;                       // ci*16 + ly
    uint4 d = *(const uint4*)(p1 + (size_t)(tb0 + img) * 16384 + (size_t)rem * 16);
    *(uint4*)(&simg[img][0][0][0] + (size_t)(rem >> 4) * 512 + (size_t)(rem & 15) * 32) = d;
  }
  __syncthreads();
  int job = tid;
  if (job >= 224) return;
  int img = job / 112;
  int rem = job % 112;
  int co8 = rem / 14;
  int oy  = rem % 14;
  float acc[8][14];
#pragma unroll
  for (int c = 0; c < 8; ++c)
#pragma unroll
    for (int ox = 0; ox < 14; ++ox) acc[c][ox] = 0.f;

  const unsigned char* ibase = &simg[img][0][0][0];
  for (int ci = 0; ci < 64; ++ci) {
    const unsigned char* rowb = ibase + ci * 512 + oy * 32;
#pragma unroll
    for (int dy = 0; dy < 3; ++dy) {
      const uint* rp = (const uint*)(rowb + dy * 32);
      uint dw0 = rp[0], dw1 = rp[1], dw2 = rp[2], dw3 = rp[3];
      float fr[16];
#pragma unroll
      for (int cc = 0; cc < 16; ++cc) {
        uint w = (cc < 4) ? dw0 : (cc < 8) ? dw1 : (cc < 12) ? dw2 : dw3;
        fr[cc] = (float)((w >> ((cc & 3) * 8)) & 255u);
      }
      const float* wbase = w2t + (size_t)((ci * 3 + dy) * 3) * 64 + co8 * 8;
#pragma unroll
      for (int dx = 0; dx < 3; ++dx) {
        float4 wa = *(const float4*)(wbase + dx * 64);
        float4 wb = *(const float4*)(wbase + dx * 64 + 4);
        float wv[8] = {wa.x, wa.y, wa.z, wa.w, wb.x, wb.y, wb.z, wb.w};
#pragma unroll
        for (int c = 0; c < 8; ++c)
#pragma unroll
          for (int ox = 0; ox < 14; ++ox)
            acc[c][ox] = fmaf(wv[c], fr[ox + dx], acc[c][ox]);
      }
    }
  }
  int tb = tb0 + img;
#pragma unroll
  for (int c = 0; c < 8; ++c) {
    int co = co8 * 8 + c;
    float inv  = g2[co] / sqrtf(v2[co] + 1e-5f);
    float bias = __fsub_rn(b2[co], __fmul_rn(m2[co], inv));
    float* op = h2 + ((size_t)tb * 64 + co) * 196 + oy * 14;
#pragma unroll
    for (int ox = 0; ox < 14; ++ox)
      op[ox] = __fadd_rn(__fmul_rn(acc[c][ox], inv), bias);
  }
}

// ---------------- LIF2 + maxpool -> p2 (u8) ----------------
__global__ __launch_bounds__(256) void k_lif2pool(const float* __restrict__ h2,
                                                  unsigned char* __restrict__ p2) {
  int t = blockIdx.x * 256 + threadIdx.x;      // < 50176 = 16*64*49
  int px = t % 7;
  int r1 = t / 7;
  int py = r1 % 7;
  int r2 = r1 / 7;
  int c = r2 & 63, b = r2 >> 6;
  const float* base = h2 + ((size_t)b * 64 + c) * 196 + (2 * py) * 14 + 2 * px;
  const size_t tstride = (size_t)16 * 64 * 196;
  unsigned char* op = p2 + (size_t)b * 3136 + c * 49 + py * 7 + px;
  const size_t otstride = (size_t)16 * 3136;
  float v00 = 0.f, v01 = 0.f, v10 = 0.f, v11 = 0.f;
#pragma unroll 4
  for (int tt = 0; tt < T_STEPS; ++tt) {
    const float* hp = base + (size_t)tt * tstride;
    float2 r0 = *(const float2*)(hp);
    float2 r1v = *(const float2*)(hp + 14);
    int s = 0;
    s |= lif_step_i(v00, r0.x);
    s |= lif_step_i(v01, r0.y);
    s |= lif_step_i(v10, r1v.x);
    s |= lif_step_i(v11, r1v.y);
    op[(size_t)tt * otstride] = (unsigned char)s;
  }
}

// ---------------- FC1: h3[tb][o] += p2[tb][:] . Wfc1[o][:] ----------------
// grid (13, 8, 2): 128tb x 128o tiles, split-K=2, atomicAdd into zeroed h3
// (exactly 2 atomic adds per cell onto 0.0 => deterministic by fp-add commutativity)
__global__ __launch_bounds__(256) void k_fc1(const unsigned char* __restrict__ p2,
                                             const float* __restrict__ wfc1,
                                             float* __restrict__ h3) {
  __shared__ float As[32][128];
  __shared__ float Bs[32][128];
  const int t = threadIdx.x;
  const int r = t & 127, half = t >> 7;
  const int tb0 = blockIdx.x * 128;
  const int o0  = blockIdx.y * 128;
  const int k0  = blockIdx.z * 1568;
  const int ig = t >> 4, jg = t & 15;
  float acc[8][8];
#pragma unroll
  for (int a = 0; a < 8; ++a)
#pragma unroll
    for (int bb = 0; bb < 8; ++bb) acc[a][bb] = 0.f;

  for (int ch = 0; ch < 49; ++ch) {
    int kb = k0 + ch * 32;
    __syncthreads();
    // stage A (spikes u8 -> f32, layout As[k][tb])
    {
      int tb = tb0 + r;
      uint4 bytes = make_uint4(0u, 0u, 0u, 0u);
      if (tb < 1600) bytes = *(const uint4*)(p2 + (size_t)tb * 3136 + kb + half * 16);
      uint w4[4] = {bytes.x, bytes.y, bytes.z, bytes.w};
#pragma unroll
      for (int j = 0; j < 16; ++j)
        As[half * 16 + j][r] = (float)((w4[j >> 2] >> ((j & 3) * 8)) & 255u);
    }
    // stage B (Bs[k][o])
    {
      const float* wrow = wfc1 + (size_t)(o0 + r) * 3136 + kb + half * 16;
#pragma unroll
      for (int j = 0; j < 4; ++j) {
        float4 d = *(const float4*)(wrow + j * 4);
        int kk = half * 16 + j * 4;
        Bs[kk + 0][r] = d.x; Bs[kk + 1][r] = d.y; Bs[kk + 2][r] = d.z; Bs[kk + 3][r] = d.w;
      }
    }
    __syncthreads();
#pragma unroll 8
    for (int kk = 0; kk < 32; ++kk) {
      float4 a0 = *(const float4*)&As[kk][ig * 8];
      float4 a1 = *(const float4*)&As[kk][ig * 8 + 4];
      float4 b0 = *(const float4*)&Bs[kk][jg * 8];
      float4 b1 = *(const float4*)&Bs[kk][jg * 8 + 4];
      float av[8] = {a0.x, a0.y, a0.z, a0.w, a1.x, a1.y, a1.z, a1.w};
      float bv[8] = {b0.x, b0.y, b0.z, b0.w, b1.x, b1.y, b1.z, b1.w};
#pragma unroll
      for (int a = 0; a < 8; ++a)
#pragma unroll
        for (int bb = 0; bb < 8; ++bb)
          acc[a][bb] = fmaf(av[a], bv[bb], acc[a][bb]);
    }
  }
#pragma unroll
  for (int a = 0; a < 8; ++a) {
    int tb = tb0 + ig * 8 + a;
    if (tb < 1600) {
#pragma unroll
      for (int bb = 0; bb < 8; ++bb)
        atomicAdd(&h3[(size_t)tb * 1024 + o0 + jg * 8 + bb], acc[a][bb]);
    }
  }
}

// ---------------- LIF3 -> s3 (u8) ----------------
__global__ __launch_bounds__(256) void k_lif3(const float* __restrict__ h3,
                                              unsigned char* __restrict__ s3) {
  int t = blockIdx.x * 256 + threadIdx.x;      // < 16384
  int o = t & 1023, b = t >> 10;
  size_t base = (size_t)b * 1024 + o;
  float v = 0.f;
#pragma unroll 5
  for (int tt = 0; tt < T_STEPS; ++tt) {
    float xv = h3[base + (size_t)tt * 16384];
    s3[base + (size_t)tt * 16384] = (unsigned char)lif_step_i(v, xv);
  }
}

// ---------------- FC2 ----------------
__global__ __launch_bounds__(64) void k_fc2(const unsigned char* __restrict__ s3,
                                            const float* __restrict__ wfc2,
                                            float* __restrict__ h4) {
  int tb = blockIdx.x;                          // < 1600
  int l = threadIdx.x;
  const unsigned char* srow = s3 + (size_t)tb * 1024;
  float p[10];
#pragma unroll
  for (int o = 0; o < 10; ++o) p[o] = 0.f;
  for (int j = 0; j < 16; ++j) {
    int k = l + j * 64;
    float s = (float)srow[k];
#pragma unroll
    for (int o = 0; o < 10; ++o)
      p[o] = fmaf(s, wfc2[o * 1024 + k], p[o]);
  }
#pragma unroll
  for (int o = 0; o < 10; ++o) {
    float v = p[o];
    for (int off = 32; off > 0; off >>= 1) v += __shfl_down(v, off, 64);
    if (l == 0) h4[(size_t)tb * 10 + o] = v;
  }
}

// ---------------- LIF4 + mean ----------------
__global__ __launch_bounds__(256) void k_lif4mean(const float* __restrict__ h4,
                                                  float* __restrict__ out) {
  int t = threadIdx.x;
  if (t >= 160) return;
  int o = t % 10, b = t / 10;
  float v = 0.f;
  int cnt = 0;
#pragma unroll 10
  for (int tt = 0; tt < T_STEPS; ++tt) {
    float xv = h4[(size_t)tt * 160 + b * 10 + o];
    cnt += lif_step_i(v, xv);
  }
  out[b * 10 + o] = (float)cnt / 100.0f;
}

extern "C" void kernel_launch(void* const* d_in, const int* in_sizes, int n_in,
                              void* d_out, int out_size, void* d_ws, size_t ws_size,
                              hipStream_t stream) {
  const float* x    = (const float*)d_in[0];
  const float* W1   = (const float*)d_in[1];
  const float* g1   = (const float*)d_in[2];
  const float* b1   = (const float*)d_in[3];
  const float* m1   = (const float*)d_in[4];
  const float* v1   = (const float*)d_in[5];
  const float* W2   = (const float*)d_in[6];
  const float* g2   = (const float*)d_in[7];
  const float* b2   = (const float*)d_in[8];
  const float* m2   = (const float*)d_in[9];
  const float* v2   = (const float*)d_in[10];
  const float* Wfc1 = (const float*)d_in[11];
  const float* Wfc2 = (const float*)d_in[12];
  float* out = (float*)d_out;
  char* ws = (char*)d_ws;

  float*         h1  = (float*)(ws + OFF_H1);
  unsigned char* p1  = (unsigned char*)(ws + OFF_P1);
  float*         w2t = (float*)(ws + OFF_W2T);
  float*         h2  = (float*)(ws + OFF_H2);
  unsigned char* p2  = (unsigned char*)(ws + OFF_P2);
  float*         h3  = (float*)(ws + OFF_H3);
  unsigned char* s3  = (unsigned char*)(ws + OFF_S3);
  float*         h4  = (float*)(ws + OFF_H4);

  k_transpose_w2<<<144, 256, 0, stream>>>(W2, w2t);
  k_zero_h3<<<1600, 256, 0, stream>>>((float4*)h3);
  k_conv1<<<3136, 256, 0, stream>>>(x, W1, g1, b1, m1, v1, h1);
  k_lif1pool<<<1024, 256, 0, stream>>>(h1, p1);
  k_conv2<<<800, 256, 0, stream>>>(p1, w2t, g2, b2, m2, v2, h2);
  k_lif2pool<<<196, 256, 0, stream>>>(h2, p2);
  dim3 gfc1(13, 8, 2);
  k_fc1<<<gfc1, 256, 0, stream>>>(p2, Wfc1, h3);
  k_lif3<<<64, 256, 0, stream>>>(h3, s3);
  k_fc2<<<1600, 64, 0, stream>>>(s3, Wfc2, h4);
  k_lif4mean<<<1, 256, 0, stream>>>(h4, out);
}